// Round 8
// baseline (178.454 us; speedup 1.0000x reference)
//
#include <hip/hip_runtime.h>
#include <hip/hip_bf16.h>
#include <math.h>

// Problem constants
#define BB 128
#define KK 32
#define JJ 1152
#define II 8
#define ZZ 16

typedef __attribute__((ext_vector_type(8))) short short8;
typedef __attribute__((ext_vector_type(4))) float floatx4;

// Workspace layout (float words): [usum | sacc | S | E | xbf | Wt]
#define N_USUM (KK * BB * ZZ)       // [k][b][z]   65536
#define N_SACC (KK * BB * ZZ)       // [k][b][z]   65536
#define N_S    (JJ * BB)            // [j][b]     147456
#define N_E    (KK * JJ * BB)       // [k][j][b] 4718592
#define N_XBF  (JJ * BB * II / 2)   // bf16 pairs  589824 float words
#define N_WT   (KK * JJ * ZZ * II / 2)

__device__ __forceinline__ float bf2f(short h) {
    unsigned int w = ((unsigned int)(unsigned short)h) << 16;
    float f; __builtin_memcpy(&f, &w, 4);
    return f;
}

// ---- Prep: x[b][j][i] fp32 -> xbf[j][b][i] bf16 ----
extern "C" __global__ __launch_bounds__(256)
void kX(const float* __restrict__ x, __hip_bfloat16* __restrict__ xbf) {
    int idx = blockIdx.x * 256 + threadIdx.x;    // [0, J*B)
    int j_in = idx & 15;
    int rest = idx >> 4;
    int b    = rest & 127;
    int j    = (rest >> 7) * 16 + j_in;
    const float4* xp = (const float4*)(x + ((size_t)b * JJ + j) * II);
    float4 a = xp[0], c = xp[1];
    union { short8 v; __hip_bfloat16 h[8]; } u;
    u.h[0] = __float2bfloat16(a.x); u.h[1] = __float2bfloat16(a.y);
    u.h[2] = __float2bfloat16(a.z); u.h[3] = __float2bfloat16(a.w);
    u.h[4] = __float2bfloat16(c.x); u.h[5] = __float2bfloat16(c.y);
    u.h[6] = __float2bfloat16(c.z); u.h[7] = __float2bfloat16(c.w);
    *(short8*)(xbf + ((size_t)j * BB + b) * II) = u.v;
}

// ---- Prep: W[k][j][i][z] fp32 -> Wt[k][j][z][i] bf16 ----
extern "C" __global__ __launch_bounds__(256)
void kW(const float* __restrict__ W, __hip_bfloat16* __restrict__ Wt) {
    int idx = blockIdx.x * 256 + threadIdx.x;    // [0, K*J*16)
    int z    = idx & 15;
    int rest = idx >> 4;
    int j    = rest % JJ;
    int k    = rest / JJ;
    const float* src = W + (((size_t)k * JJ + j) * II) * ZZ + z;
    union { short8 v; __hip_bfloat16 h[8]; } u;
#pragma unroll
    for (int i = 0; i < II; ++i) u.h[i] = __float2bfloat16(src[i * ZZ]);
    *(short8*)(Wt + (((size_t)k * JJ + j) * ZZ + z) * II) = u.v;
}

// ---- Pass A: usum[k][b][z] = sum_{j,i} x*W  (j-quads in K; j-sum in C-frag) ----
// grid (KK, 8 bt, 8 js), block 64. D lane: b=lane&15, z=(lane>>4)*4+r.
extern "C" __global__ __launch_bounds__(64)
void kA(const __hip_bfloat16* __restrict__ xbf,
        const __hip_bfloat16* __restrict__ Wt, float* __restrict__ usum) {
    const int k  = blockIdx.x;
    const int bt = blockIdx.y;
    const int js = blockIdx.z;
    const int l  = threadIdx.x;
    const int n  = l & 15;
    const int g  = l >> 4;
    const int b  = bt * 16 + n;

    floatx4 acc = {0.f, 0.f, 0.f, 0.f};
#pragma unroll 4
    for (int q = 0; q < 36; ++q) {
        int j = (js * 36 + q) * 4 + g;
        short8 a  = *(const short8*)(Wt  + (((size_t)k * JJ + j) * ZZ + n) * II);
        short8 xv = *(const short8*)(xbf + ((size_t)j * BB + b) * II);
        acc = __builtin_amdgcn_mfma_f32_16x16x32_bf16(a, xv, acc, 0, 0, 0);
    }
#pragma unroll
    for (int r = 0; r < 4; ++r)
        unsafeAtomicAdd(&usum[((size_t)k * BB + b) * ZZ + g * 4 + r], acc[r]);
}

// ---- Pass B: E[k][j][b] = exp(dp/4); S[j][b] = sum_k E  (all k in-block) ----
// grid (JJ/4, 8 bt), block 64. No atomics.
extern "C" __global__ __launch_bounds__(64)
void kB(const __hip_bfloat16* __restrict__ xbf,
        const __hip_bfloat16* __restrict__ Wt, const float* __restrict__ usum,
        float* __restrict__ S, float* __restrict__ E) {
    const int jt = blockIdx.x;
    const int bt = blockIdx.y;
    const int l  = threadIdx.x;
    const int n  = l & 15;
    const int g  = l >> 4;
    const int b  = bt * 16 + n;
    const int j0 = jt * 4;

    short8 xv[4];
#pragma unroll
    for (int jl = 0; jl < 4; ++jl)
        xv[jl] = *(const short8*)(xbf + ((size_t)(j0 + jl) * BB + b) * II);

    float Sacc[4] = {0.f, 0.f, 0.f, 0.f};
#pragma unroll 2
    for (int k = 0; k < KK; ++k) {
        floatx4 us = *(const floatx4*)(usum + ((size_t)k * BB + b) * ZZ + g * 4);
#pragma unroll
        for (int jl = 0; jl < 4; ++jl) {
            short8 a = *(const short8*)(Wt + (((size_t)k * JJ + j0 + jl) * ZZ + n) * II);
            floatx4 c0 = {0.f, 0.f, 0.f, 0.f};
            floatx4 u4 = __builtin_amdgcn_mfma_f32_16x16x32_bf16(a, xv[jl], c0, 0, 0, 0);
            float dp = u4[0] * us[0];
            dp = fmaf(u4[1], us[1], dp);
            dp = fmaf(u4[2], us[2], dp);
            dp = fmaf(u4[3], us[3], dp);
            dp += __shfl_xor(dp, 16);
            dp += __shfl_xor(dp, 32);
            float e = __expf(dp * 0.0625f);   // 0.25 softmax scale * 0.25 K-dup
            Sacc[jl] += e;
            if (g == 0) E[((size_t)k * JJ + j0 + jl) * BB + b] = e;
        }
    }
    if (g == 0) {
#pragma unroll
        for (int jl = 0; jl < 4; ++jl)
            S[(size_t)(j0 + jl) * BB + b] = Sacc[jl];
    }
}

// ---- Pass C: sacc[k][b][z] += sum_j u * c  (c folded into B-operand) ----
// grid (KK, 8 bt, 8 js), block 64. j-sum in C-frag; one atomic set per wave.
extern "C" __global__ __launch_bounds__(64)
void kC(const __hip_bfloat16* __restrict__ xbf,
        const __hip_bfloat16* __restrict__ Wt, const float* __restrict__ bias,
        const float* __restrict__ S, const float* __restrict__ E,
        float* __restrict__ sacc) {
    const int k  = blockIdx.x;
    const int bt = blockIdx.y;
    const int js = blockIdx.z;
    const int l  = threadIdx.x;
    const int n  = l & 15;
    const int g  = l >> 4;
    const int b  = bt * 16 + n;

    floatx4 acc = {0.f, 0.f, 0.f, 0.f};
#pragma unroll 4
    for (int q = 0; q < 36; ++q) {
        int j = (js * 36 + q) * 4 + g;
        float e  = E[((size_t)k * JJ + j) * BB + b];
        float Sv = S[(size_t)j * BB + b];
        float bj = bias[(size_t)k * JJ + j];
        float c  = fmaf(e, __builtin_amdgcn_rcpf(Sv), bj);
        union { short8 v; short s[8]; } xu, xs;
        xu.v = *(const short8*)(xbf + ((size_t)j * BB + b) * II);
#pragma unroll
        for (int t = 0; t < 8; ++t) {
            __hip_bfloat16 hv = __float2bfloat16(bf2f(xu.s[t]) * c);
            __builtin_memcpy(&xs.s[t], &hv, 2);
        }
        short8 a = *(const short8*)(Wt + (((size_t)k * JJ + j) * ZZ + n) * II);
        acc = __builtin_amdgcn_mfma_f32_16x16x32_bf16(a, xs.v, acc, 0, 0, 0);
    }
#pragma unroll
    for (int r = 0; r < 4; ++r)
        unsafeAtomicAdd(&sacc[((size_t)k * BB + b) * ZZ + g * 4 + r], acc[r]);
}

// ---- Pass D: squash, sacc[k][b][z] -> out[b][k][z] ----
extern "C" __global__ __launch_bounds__(256)
void kD(const float* __restrict__ sacc, float* __restrict__ out) {
    int p = blockIdx.x * blockDim.x + threadIdx.x;
    if (p >= KK * BB) return;
    int k = p >> 7;
    int b = p & 127;
    const floatx4* sp = (const floatx4*)(sacc + ((size_t)k * BB + b) * ZZ);
    float v[ZZ];
    float nsq = 0.f;
#pragma unroll
    for (int q = 0; q < 4; ++q) {
        floatx4 t = sp[q];
#pragma unroll
        for (int r = 0; r < 4; ++r) {
            v[q * 4 + r] = t[r];
            nsq = fmaf(t[r], t[r], nsq);
        }
    }
    float nr = sqrtf(nsq);
    float scale = (1.f - 1.f / (__expf(nr) + 1e-20f)) / (nr + 1e-20f);
#pragma unroll
    for (int z = 0; z < ZZ; ++z)
        out[((size_t)b * KK + k) * ZZ + z] = v[z] * scale;
}

extern "C" void kernel_launch(void* const* d_in, const int* in_sizes, int n_in,
                              void* d_out, int out_size, void* d_ws, size_t ws_size,
                              hipStream_t stream) {
    const float* x    = (const float*)d_in[0];
    const float* W    = (const float*)d_in[1];
    const float* bias = (const float*)d_in[2];
    float*       out  = (float*)d_out;

    float* ws   = (float*)d_ws;
    float* usum = ws;                          // [k][b][z]
    float* sacc = ws + N_USUM;                 // [k][b][z]
    float* S    = ws + N_USUM + N_SACC;        // [j][b]
    float* E    = ws + N_USUM + N_SACC + N_S;  // [k][j][b]
    __hip_bfloat16* xbf = (__hip_bfloat16*)(ws + N_USUM + N_SACC + N_S + N_E);
    __hip_bfloat16* Wt  = xbf + (size_t)JJ * BB * II;

    // Only usum+sacc need zeroing (S, E fully overwritten).
    hipMemsetAsync(d_ws, 0, (size_t)(N_USUM + N_SACC) * sizeof(float), stream);

    kX<<<(JJ * BB) / 256, 256, 0, stream>>>(x, xbf);
    kW<<<(KK * JJ * ZZ) / 256, 256, 0, stream>>>(W, Wt);

    kA<<<dim3(KK, 8, 8), 64, 0, stream>>>(xbf, Wt, usum);
    kB<<<dim3(JJ / 4, 8), 64, 0, stream>>>(xbf, Wt, usum, S, E);
    kC<<<dim3(KK, 8, 8), 64, 0, stream>>>(xbf, Wt, bias, S, E, sacc);
    kD<<<(KK * BB + 255) / 256, 256, 0, stream>>>(sacc, out);
}

// Round 9
// 150.650 us; speedup vs baseline: 1.1846x; 1.1846x over previous
//
#include <hip/hip_runtime.h>
#include <hip/hip_bf16.h>
#include <math.h>

// Problem constants
#define BB 128
#define KK 32
#define JJ 1152
#define II 8
#define ZZ 16
#define NJS 8                      // j-split for kA/kC partials

typedef __attribute__((ext_vector_type(8))) short short8;
typedef __attribute__((ext_vector_type(4))) float floatx4;

// Workspace float-word layout: [usum | usum_p | sacc_p | S | E | xbf | Wt]
#define N_USUM  (KK * BB * ZZ)            // 65536
#define N_USUMP (NJS * KK * BB * ZZ)      // 524288
#define N_SACCP (NJS * KK * BB * ZZ)      // 524288
#define N_S     (JJ * BB)                 // 147456
#define N_E     ((size_t)KK * JJ * BB)    // 4718592

__device__ __forceinline__ float bf2f(short h) {
    unsigned int w = ((unsigned int)(unsigned short)h) << 16;
    float f; __builtin_memcpy(&f, &w, 4);
    return f;
}

// ---- Prep: x[b][j][i] fp32 -> xbf[j][b][i] bf16 ----
extern "C" __global__ __launch_bounds__(256)
void kX(const float* __restrict__ x, __hip_bfloat16* __restrict__ xbf) {
    int idx = blockIdx.x * 256 + threadIdx.x;    // [0, J*B)
    int j_in = idx & 15;
    int rest = idx >> 4;
    int b    = rest & 127;
    int j    = (rest >> 7) * 16 + j_in;
    const float4* xp = (const float4*)(x + ((size_t)b * JJ + j) * II);
    float4 a = xp[0], c = xp[1];
    union { short8 v; __hip_bfloat16 h[8]; } u;
    u.h[0] = __float2bfloat16(a.x); u.h[1] = __float2bfloat16(a.y);
    u.h[2] = __float2bfloat16(a.z); u.h[3] = __float2bfloat16(a.w);
    u.h[4] = __float2bfloat16(c.x); u.h[5] = __float2bfloat16(c.y);
    u.h[6] = __float2bfloat16(c.z); u.h[7] = __float2bfloat16(c.w);
    *(short8*)(xbf + ((size_t)j * BB + b) * II) = u.v;
}

// ---- Prep: W[k][j][i][z] fp32 -> Wt[k][j][z][i] bf16 ----
extern "C" __global__ __launch_bounds__(256)
void kW(const float* __restrict__ W, __hip_bfloat16* __restrict__ Wt) {
    int idx = blockIdx.x * 256 + threadIdx.x;    // [0, K*J*16)
    int z    = idx & 15;
    int rest = idx >> 4;
    int j    = rest % JJ;
    int k    = rest / JJ;
    const float* src = W + (((size_t)k * JJ + j) * II) * ZZ + z;
    union { short8 v; __hip_bfloat16 h[8]; } u;
#pragma unroll
    for (int i = 0; i < II; ++i) u.h[i] = __float2bfloat16(src[i * ZZ]);
    *(short8*)(Wt + (((size_t)k * JJ + j) * ZZ + z) * II) = u.v;
}

// ---- Pass A: usum_p[js][k][b][z] = partial sum_{j,i} x*W ----
// grid (KK, 8 bt, NJS), block 64. 4 independent MFMA accumulator chains.
extern "C" __global__ __launch_bounds__(64)
void kA(const __hip_bfloat16* __restrict__ xbf,
        const __hip_bfloat16* __restrict__ Wt, float* __restrict__ usum_p) {
    const int k  = blockIdx.x;
    const int bt = blockIdx.y;
    const int js = blockIdx.z;
    const int l  = threadIdx.x;
    const int n  = l & 15;
    const int g  = l >> 4;
    const int b  = bt * 16 + n;

    floatx4 acc[4];
#pragma unroll
    for (int s = 0; s < 4; ++s) acc[s] = (floatx4){0.f, 0.f, 0.f, 0.f};

#pragma unroll 3
    for (int q4 = 0; q4 < 9; ++q4) {
#pragma unroll
        for (int s = 0; s < 4; ++s) {
            int j = (js * 36 + q4 * 4 + s) * 4 + g;
            short8 a  = *(const short8*)(Wt  + (((size_t)k * JJ + j) * ZZ + n) * II);
            short8 xv = *(const short8*)(xbf + ((size_t)j * BB + b) * II);
            acc[s] = __builtin_amdgcn_mfma_f32_16x16x32_bf16(a, xv, acc[s], 0, 0, 0);
        }
    }
    floatx4 r = acc[0] + acc[1] + acc[2] + acc[3];
    *(floatx4*)(usum_p + (((size_t)js * KK + k) * BB + b) * ZZ + g * 4) = r;
}

// ---- kR: usum[k][b][z] = sum_js usum_p ----
extern "C" __global__ __launch_bounds__(256)
void kR(const float* __restrict__ usum_p, float* __restrict__ usum) {
    int idx = blockIdx.x * 256 + threadIdx.x;    // [0, 16384) float4s
    floatx4 s = (floatx4){0.f, 0.f, 0.f, 0.f};
#pragma unroll
    for (int js = 0; js < NJS; ++js)
        s += *(const floatx4*)(usum_p + (size_t)js * (KK * BB * ZZ) + (size_t)idx * 4);
    *(floatx4*)(usum + (size_t)idx * 4) = s;
}

// ---- Pass B: E[k][j][b] = exp(dp/4); S[j][b] = sum_k E ----
// grid (JJ/4, 8 bt), block 256 (4 waves, 8 k's each). LDS reduce for S.
extern "C" __global__ __launch_bounds__(256)
void kB(const __hip_bfloat16* __restrict__ xbf,
        const __hip_bfloat16* __restrict__ Wt, const float* __restrict__ usum,
        float* __restrict__ S, float* __restrict__ E) {
    __shared__ float Sred[4 * 4 * 16];   // [wave][jl][n]
    const int jt = blockIdx.x;
    const int bt = blockIdx.y;
    const int t  = threadIdx.x;
    const int w  = t >> 6;
    const int l  = t & 63;
    const int n  = l & 15;
    const int g  = l >> 4;
    const int b  = bt * 16 + n;
    const int j0 = jt * 4;

    short8 xv[4];
#pragma unroll
    for (int jl = 0; jl < 4; ++jl)
        xv[jl] = *(const short8*)(xbf + ((size_t)(j0 + jl) * BB + b) * II);

    float Sacc[4] = {0.f, 0.f, 0.f, 0.f};
#pragma unroll 2
    for (int kk = 0; kk < 8; ++kk) {
        const int k = w * 8 + kk;
        floatx4 us = *(const floatx4*)(usum + ((size_t)k * BB + b) * ZZ + g * 4);
#pragma unroll
        for (int jl = 0; jl < 4; ++jl) {
            short8 a = *(const short8*)(Wt + (((size_t)k * JJ + j0 + jl) * ZZ + n) * II);
            floatx4 c0 = {0.f, 0.f, 0.f, 0.f};
            floatx4 u4 = __builtin_amdgcn_mfma_f32_16x16x32_bf16(a, xv[jl], c0, 0, 0, 0);
            float dp = u4[0] * us[0];
            dp = fmaf(u4[1], us[1], dp);
            dp = fmaf(u4[2], us[2], dp);
            dp = fmaf(u4[3], us[3], dp);
            dp += __shfl_xor(dp, 16);
            dp += __shfl_xor(dp, 32);
            float e = __expf(dp * 0.0625f);   // 0.25 softmax scale * 0.25 K-dup
            Sacc[jl] += e;
            if (g == 0) E[((size_t)k * JJ + j0 + jl) * BB + b] = e;
        }
    }
    if (g == 0) {
#pragma unroll
        for (int jl = 0; jl < 4; ++jl) Sred[(w * 4 + jl) * 16 + n] = Sacc[jl];
    }
    __syncthreads();
    if (t < 64) {
        int jl = t >> 4, n2 = t & 15;
        float s = Sred[(0 * 4 + jl) * 16 + n2] + Sred[(1 * 4 + jl) * 16 + n2]
                + Sred[(2 * 4 + jl) * 16 + n2] + Sred[(3 * 4 + jl) * 16 + n2];
        S[(size_t)(j0 + jl) * BB + bt * 16 + n2] = s;
    }
}

// ---- Pass C: sacc_p[js][k][b][z] = partial sum_j u*(E/S+bias) ----
// grid (KK, 8 bt, NJS), block 64. c folded into B-operand; 4 acc chains.
extern "C" __global__ __launch_bounds__(64)
void kC(const __hip_bfloat16* __restrict__ xbf,
        const __hip_bfloat16* __restrict__ Wt, const float* __restrict__ bias,
        const float* __restrict__ S, const float* __restrict__ E,
        float* __restrict__ sacc_p) {
    const int k  = blockIdx.x;
    const int bt = blockIdx.y;
    const int js = blockIdx.z;
    const int l  = threadIdx.x;
    const int n  = l & 15;
    const int g  = l >> 4;
    const int b  = bt * 16 + n;

    floatx4 acc[4];
#pragma unroll
    for (int s = 0; s < 4; ++s) acc[s] = (floatx4){0.f, 0.f, 0.f, 0.f};

#pragma unroll 3
    for (int q4 = 0; q4 < 9; ++q4) {
#pragma unroll
        for (int s = 0; s < 4; ++s) {
            int j = (js * 36 + q4 * 4 + s) * 4 + g;
            float e  = E[((size_t)k * JJ + j) * BB + b];
            float Sv = S[(size_t)j * BB + b];
            float bj = bias[(size_t)k * JJ + j];
            float c  = fmaf(e, __builtin_amdgcn_rcpf(Sv), bj);
            union { short8 v; short sv[8]; } xu, xs;
            xu.v = *(const short8*)(xbf + ((size_t)j * BB + b) * II);
#pragma unroll
            for (int tt = 0; tt < 8; ++tt) {
                __hip_bfloat16 hv = __float2bfloat16(bf2f(xu.sv[tt]) * c);
                __builtin_memcpy(&xs.sv[tt], &hv, 2);
            }
            short8 a = *(const short8*)(Wt + (((size_t)k * JJ + j) * ZZ + n) * II);
            acc[s] = __builtin_amdgcn_mfma_f32_16x16x32_bf16(a, xs.v, acc[s], 0, 0, 0);
        }
    }
    floatx4 r = acc[0] + acc[1] + acc[2] + acc[3];
    *(floatx4*)(sacc_p + (((size_t)js * KK + k) * BB + b) * ZZ + g * 4) = r;
}

// ---- Pass D: reduce sacc_p over js + squash -> out[b][k][z] ----
extern "C" __global__ __launch_bounds__(256)
void kD(const float* __restrict__ sacc_p, float* __restrict__ out) {
    int p = blockIdx.x * blockDim.x + threadIdx.x;
    if (p >= KK * BB) return;
    int k = p >> 7;
    int b = p & 127;
    floatx4 v4[4];
#pragma unroll
    for (int q = 0; q < 4; ++q) v4[q] = (floatx4){0.f, 0.f, 0.f, 0.f};
#pragma unroll
    for (int js = 0; js < NJS; ++js) {
        const floatx4* sp = (const floatx4*)(sacc_p +
            (((size_t)js * KK + k) * BB + b) * ZZ);
#pragma unroll
        for (int q = 0; q < 4; ++q) v4[q] += sp[q];
    }
    float nsq = 0.f;
#pragma unroll
    for (int q = 0; q < 4; ++q)
#pragma unroll
        for (int r = 0; r < 4; ++r) nsq = fmaf(v4[q][r], v4[q][r], nsq);
    float nr = sqrtf(nsq);
    float scale = (1.f - 1.f / (__expf(nr) + 1e-20f)) / (nr + 1e-20f);
#pragma unroll
    for (int q = 0; q < 4; ++q)
#pragma unroll
        for (int r = 0; r < 4; ++r)
            out[((size_t)b * KK + k) * ZZ + q * 4 + r] = v4[q][r] * scale;
}

extern "C" void kernel_launch(void* const* d_in, const int* in_sizes, int n_in,
                              void* d_out, int out_size, void* d_ws, size_t ws_size,
                              hipStream_t stream) {
    const float* x    = (const float*)d_in[0];
    const float* W    = (const float*)d_in[1];
    const float* bias = (const float*)d_in[2];
    float*       out  = (float*)d_out;

    float* ws     = (float*)d_ws;
    float* usum   = ws;
    float* usum_p = usum + N_USUM;
    float* sacc_p = usum_p + N_USUMP;
    float* S      = sacc_p + N_SACCP;
    float* E      = S + N_S;
    __hip_bfloat16* xbf = (__hip_bfloat16*)(E + N_E);
    __hip_bfloat16* Wt  = xbf + (size_t)JJ * BB * II;

    // No memset needed: every workspace word is written before it is read.

    kX<<<(JJ * BB) / 256, 256, 0, stream>>>(x, xbf);
    kW<<<(KK * JJ * ZZ) / 256, 256, 0, stream>>>(W, Wt);

    kA<<<dim3(KK, 8, NJS), 64, 0, stream>>>(xbf, Wt, usum_p);
    kR<<<64, 256, 0, stream>>>(usum_p, usum);
    kB<<<dim3(JJ / 4, 8), 256, 0, stream>>>(xbf, Wt, usum, S, E);
    kC<<<dim3(KK, 8, NJS), 64, 0, stream>>>(xbf, Wt, bias, S, E, sacc_p);
    kD<<<(KK * BB + 255) / 256, 256, 0, stream>>>(sacc_p, out);
}

// Round 11
// 134.155 us; speedup vs baseline: 1.3302x; 1.1230x over previous
//
#include <hip/hip_runtime.h>
#include <hip/hip_bf16.h>
#include <math.h>

// Problem constants
#define BB 128
#define KK 32
#define JJ 1152
#define II 8
#define ZZ 16

#define NJSA 48            // kA: 48 j-groups of 6 quads (24 j each) -> 48*6*4 = 1152 ✓
#define NJT  144           // kBC: 144 j-tiles of 8 j

typedef __attribute__((ext_vector_type(8))) short short8;
typedef __attribute__((ext_vector_type(4))) float floatx4;

// Workspace float-word layout: [usum | usum_p | sacc_p | xbf | Wt]
#define N_USUM  (KK * BB * ZZ)                   // 65536
#define N_USUMP (NJSA * KK * BB * ZZ)            // 3145728
#define N_SACCP ((size_t)NJT * KK * BB * ZZ)     // 9437184

__device__ __forceinline__ float bf2f(short h) {
    unsigned int w = ((unsigned int)(unsigned short)h) << 16;
    float f; __builtin_memcpy(&f, &w, 4);
    return f;
}

// ---- Prep: x[b][j][i] fp32 -> xbf[j][b][i] bf16 ----
extern "C" __global__ __launch_bounds__(256)
void kX(const float* __restrict__ x, __hip_bfloat16* __restrict__ xbf) {
    int idx = blockIdx.x * 256 + threadIdx.x;    // [0, J*B)
    int j_in = idx & 15;
    int rest = idx >> 4;
    int b    = rest & 127;
    int j    = (rest >> 7) * 16 + j_in;
    const float4* xp = (const float4*)(x + ((size_t)b * JJ + j) * II);
    float4 a = xp[0], c = xp[1];
    union { short8 v; __hip_bfloat16 h[8]; } u;
    u.h[0] = __float2bfloat16(a.x); u.h[1] = __float2bfloat16(a.y);
    u.h[2] = __float2bfloat16(a.z); u.h[3] = __float2bfloat16(a.w);
    u.h[4] = __float2bfloat16(c.x); u.h[5] = __float2bfloat16(c.y);
    u.h[6] = __float2bfloat16(c.z); u.h[7] = __float2bfloat16(c.w);
    *(short8*)(xbf + ((size_t)j * BB + b) * II) = u.v;
}

// ---- Prep: W[k][j][i][z] fp32 -> Wt[k][j][z][i] bf16 ----
extern "C" __global__ __launch_bounds__(256)
void kW(const float* __restrict__ W, __hip_bfloat16* __restrict__ Wt) {
    int idx = blockIdx.x * 256 + threadIdx.x;    // [0, K*J*16)
    int z    = idx & 15;
    int rest = idx >> 4;
    int j    = rest % JJ;
    int k    = rest / JJ;
    const float* src = W + (((size_t)k * JJ + j) * II) * ZZ + z;
    union { short8 v; __hip_bfloat16 h[8]; } u;
#pragma unroll
    for (int i = 0; i < II; ++i) u.h[i] = __float2bfloat16(src[i * ZZ]);
    *(short8*)(Wt + (((size_t)k * JJ + j) * ZZ + z) * II) = u.v;
}

// ---- Pass A: usum_p[js][k][b][z] partials; 4 k per wave, 6 j-quads ----
// grid (8 kt, 8 bt, NJSA), block 64. Full j coverage: 48*6*4 = 1152.
extern "C" __global__ __launch_bounds__(64)
void kA(const __hip_bfloat16* __restrict__ xbf,
        const __hip_bfloat16* __restrict__ Wt, float* __restrict__ usum_p) {
    const int kt = blockIdx.x;
    const int bt = blockIdx.y;
    const int js = blockIdx.z;
    const int l  = threadIdx.x;
    const int n  = l & 15;
    const int g  = l >> 4;
    const int b  = bt * 16 + n;

    short8 xv[6];
#pragma unroll
    for (int q = 0; q < 6; ++q) {
        int j = (js * 6 + q) * 4 + g;
        xv[q] = *(const short8*)(xbf + ((size_t)j * BB + b) * II);
    }

    floatx4 acc[4];
#pragma unroll
    for (int kk = 0; kk < 4; ++kk) acc[kk] = (floatx4){0.f, 0.f, 0.f, 0.f};

#pragma unroll
    for (int kk = 0; kk < 4; ++kk) {
        const int k = kt * 4 + kk;
#pragma unroll
        for (int q = 0; q < 6; ++q) {
            int j = (js * 6 + q) * 4 + g;
            short8 a = *(const short8*)(Wt + (((size_t)k * JJ + j) * ZZ + n) * II);
            acc[kk] = __builtin_amdgcn_mfma_f32_16x16x32_bf16(a, xv[q], acc[kk], 0, 0, 0);
        }
    }
#pragma unroll
    for (int kk = 0; kk < 4; ++kk) {
        const int k = kt * 4 + kk;
        *(floatx4*)(usum_p + (((size_t)js * KK + k) * BB + b) * ZZ + g * 4) = acc[kk];
    }
}

// ---- kR: usum[k][b][z] = sum_js usum_p ----
extern "C" __global__ __launch_bounds__(256)
void kR(const float* __restrict__ usum_p, float* __restrict__ usum) {
    int idx = blockIdx.x * 256 + threadIdx.x;    // [0, 16384) float4s
    floatx4 s = (floatx4){0.f, 0.f, 0.f, 0.f};
#pragma unroll 8
    for (int js = 0; js < NJSA; ++js)
        s += *(const floatx4*)(usum_p + (size_t)js * N_USUM + (size_t)idx * 4);
    *(floatx4*)(usum + (size_t)idx * 4) = s;
}

// ---- Fused B+C: per (8-j, 16-b) tile over ALL 32 k.
// Phase 1: e[k][jl][b] -> LDS, S reduced in LDS (no global E/S).
// Phase 2: j-packed MFMA with c folded into B-operand -> sacc_p[jt][k][b][z].
extern "C" __global__ __launch_bounds__(256)
void kBC(const __hip_bfloat16* __restrict__ xbf,
         const __hip_bfloat16* __restrict__ Wt,
         const float* __restrict__ usum, const float* __restrict__ bias,
         float* __restrict__ sacc_p) {
    __shared__ float eS[KK * 8 * 16];   // 16 KB: e[k][jl][n]
    __shared__ float Sw[4 * 8 * 16];    // per-wave S partials
    __shared__ float rS[8 * 16];        // 1/S[jl][n]

    const int jt = blockIdx.x;          // 0..143
    const int bt = blockIdx.y;          // 0..7
    const int t  = threadIdx.x;
    const int w  = t >> 6;
    const int l  = t & 63;
    const int n  = l & 15;
    const int g  = l >> 4;
    const int b  = bt * 16 + n;
    const int j0 = jt * 8;

    // Preload the 8 x-fragments (lane-uniform jl indexing -> stays in regs)
    short8 xv[8];
#pragma unroll
    for (int jl = 0; jl < 8; ++jl)
        xv[jl] = *(const short8*)(xbf + ((size_t)(j0 + jl) * BB + b) * II);

    // ---- Phase 1: e + per-wave S ----
    float Sacc[8];
#pragma unroll
    for (int jl = 0; jl < 8; ++jl) Sacc[jl] = 0.f;

#pragma unroll 2
    for (int kk = 0; kk < 8; ++kk) {
        const int k = w * 8 + kk;
        floatx4 us = *(const floatx4*)(usum + ((size_t)k * BB + b) * ZZ + g * 4);
#pragma unroll
        for (int jl = 0; jl < 8; ++jl) {
            short8 a = *(const short8*)(Wt + (((size_t)k * JJ + j0 + jl) * ZZ + n) * II);
            floatx4 c0 = {0.f, 0.f, 0.f, 0.f};
            floatx4 u4 = __builtin_amdgcn_mfma_f32_16x16x32_bf16(a, xv[jl], c0, 0, 0, 0);
            float dp = u4[0] * us[0];
            dp = fmaf(u4[1], us[1], dp);
            dp = fmaf(u4[2], us[2], dp);
            dp = fmaf(u4[3], us[3], dp);
            dp += __shfl_xor(dp, 16);
            dp += __shfl_xor(dp, 32);
            float e = __expf(dp * 0.0625f);   // 0.25 softmax * 0.25 K-dup
            Sacc[jl] += e;
            if (g == 0) eS[(k * 8 + jl) * 16 + n] = e;
        }
    }
    if (g == 0) {
#pragma unroll
        for (int jl = 0; jl < 8; ++jl) Sw[(w * 8 + jl) * 16 + n] = Sacc[jl];
    }
    __syncthreads();
    if (t < 128) {
        int jl = t >> 4, n2 = t & 15;
        float s = Sw[(0 * 8 + jl) * 16 + n2] + Sw[(1 * 8 + jl) * 16 + n2]
                + Sw[(2 * 8 + jl) * 16 + n2] + Sw[(3 * 8 + jl) * 16 + n2];
        rS[jl * 16 + n2] = __builtin_amdgcn_rcpf(s);
    }
    __syncthreads();

    // ---- Phase 2: sacc partial, c folded into B-operand ----
    // Per-lane j = j0 + quad*4 + g (quad is uniform); reload raw x per quad.
    float xf[2][8];
#pragma unroll
    for (int quad = 0; quad < 2; ++quad) {
        union { short8 v; short s[8]; } xr;
        xr.v = *(const short8*)(xbf + ((size_t)(j0 + quad * 4 + g) * BB + b) * II);
#pragma unroll
        for (int i = 0; i < II; ++i) xf[quad][i] = bf2f(xr.s[i]);
    }

    floatx4 acc[8];
#pragma unroll
    for (int kk = 0; kk < 8; ++kk) acc[kk] = (floatx4){0.f, 0.f, 0.f, 0.f};

#pragma unroll 2
    for (int kk = 0; kk < 8; ++kk) {
        const int k = w * 8 + kk;
#pragma unroll
        for (int quad = 0; quad < 2; ++quad) {
            const int jl = quad * 4 + g;
            const int j  = j0 + jl;
            float e  = eS[(k * 8 + jl) * 16 + n];
            float c  = fmaf(e, rS[jl * 16 + n], bias[(size_t)k * JJ + j]);
            union { short8 v; short s[8]; } xs;
#pragma unroll
            for (int i = 0; i < II; ++i) {
                __hip_bfloat16 hv = __float2bfloat16(xf[quad][i] * c);
                __builtin_memcpy(&xs.s[i], &hv, 2);
            }
            short8 a = *(const short8*)(Wt + (((size_t)k * JJ + j) * ZZ + n) * II);
            acc[kk] = __builtin_amdgcn_mfma_f32_16x16x32_bf16(a, xs.v, acc[kk], 0, 0, 0);
        }
    }
#pragma unroll
    for (int kk = 0; kk < 8; ++kk) {
        const int k = w * 8 + kk;
        *(floatx4*)(sacc_p + (((size_t)jt * KK + k) * BB + b) * ZZ + g * 4) = acc[kk];
    }
}

// ---- Pass D: 144-way reduce of sacc_p + squash -> out[b][k][z] ----
// One thread per z-quarter; 4 lanes (same (k,b)) combine nsq via shfl.
extern "C" __global__ __launch_bounds__(256)
void kD(const float* __restrict__ sacc_p, float* __restrict__ out) {
    int p  = blockIdx.x * 256 + threadIdx.x;   // [0, KK*BB*4)
    int q  = p & 3;
    int kb = p >> 2;
    int k  = kb >> 7;
    int b  = kb & 127;

    floatx4 v = (floatx4){0.f, 0.f, 0.f, 0.f};
#pragma unroll 8
    for (int jt = 0; jt < NJT; ++jt)
        v += *(const floatx4*)(sacc_p + (((size_t)jt * KK + k) * BB + b) * ZZ + q * 4);

    float nsq = v[0] * v[0];
    nsq = fmaf(v[1], v[1], nsq);
    nsq = fmaf(v[2], v[2], nsq);
    nsq = fmaf(v[3], v[3], nsq);
    nsq += __shfl_xor(nsq, 1);
    nsq += __shfl_xor(nsq, 2);

    float nr = sqrtf(nsq);
    float scale = (1.f - 1.f / (__expf(nr) + 1e-20f)) / (nr + 1e-20f);
    floatx4 o = v * scale;
    *(floatx4*)(out + ((size_t)b * KK + k) * ZZ + q * 4) = o;
}

extern "C" void kernel_launch(void* const* d_in, const int* in_sizes, int n_in,
                              void* d_out, int out_size, void* d_ws, size_t ws_size,
                              hipStream_t stream) {
    const float* x    = (const float*)d_in[0];
    const float* W    = (const float*)d_in[1];
    const float* bias = (const float*)d_in[2];
    float*       out  = (float*)d_out;

    float* ws     = (float*)d_ws;
    float* usum   = ws;
    float* usum_p = usum + N_USUM;
    float* sacc_p = usum_p + N_USUMP;
    __hip_bfloat16* xbf = (__hip_bfloat16*)(sacc_p + N_SACCP);
    __hip_bfloat16* Wt  = xbf + (size_t)JJ * BB * II;

    // No memset: every workspace word is written before it is read.

    kX<<<(JJ * BB) / 256, 256, 0, stream>>>(x, xbf);
    kW<<<(KK * JJ * ZZ) / 256, 256, 0, stream>>>(W, Wt);

    kA<<<dim3(8, 8, NJSA), 64, 0, stream>>>(xbf, Wt, usum_p);
    kR<<<64, 256, 0, stream>>>(usum_p, usum);
    kBC<<<dim3(NJT, 8), 256, 0, stream>>>(xbf, Wt, usum, bias, sacc_p);
    kD<<<(KK * BB * 4) / 256, 256, 0, stream>>>(sacc_p, out);
}

// Round 12
// 132.448 us; speedup vs baseline: 1.3473x; 1.0129x over previous
//
#include <hip/hip_runtime.h>
#include <hip/hip_bf16.h>
#include <math.h>

// Problem constants
#define BB 128
#define KK 32
#define JJ 1152
#define II 8
#define ZZ 16

#define NJSA 48            // kA: 48 j-groups of 6 quads (24 j each) -> 48*6*4 = 1152
#define NJT  144           // kBC: 144 j-tiles of 8 j

typedef __attribute__((ext_vector_type(8))) short short8;
typedef __attribute__((ext_vector_type(4))) float floatx4;

// Workspace float-word layout: [usum | usum_p | sacc_p | xbf | Wt]
#define N_USUM  (KK * BB * ZZ)                   // 65536
#define N_USUMP (NJSA * KK * BB * ZZ)            // 3145728
#define N_SACCP ((size_t)NJT * KK * BB * ZZ)     // 9437184

#define KX_BLOCKS ((JJ * BB) / 256)              // 576
#define KW_BLOCKS ((KK * JJ * ZZ) / 256)         // 2304

__device__ __forceinline__ float bf2f(short h) {
    unsigned int w = ((unsigned int)(unsigned short)h) << 16;
    float f; __builtin_memcpy(&f, &w, 4);
    return f;
}

// ---- Merged prep: x -> xbf[j][b][i] bf16 ; W -> Wt[k][j][z][i] bf16 ----
extern "C" __global__ __launch_bounds__(256)
void kP(const float* __restrict__ x, const float* __restrict__ W,
        __hip_bfloat16* __restrict__ xbf, __hip_bfloat16* __restrict__ Wt) {
    if (blockIdx.x < KX_BLOCKS) {
        int idx = blockIdx.x * 256 + threadIdx.x;    // [0, J*B)
        int j_in = idx & 15;
        int rest = idx >> 4;
        int b    = rest & 127;
        int j    = (rest >> 7) * 16 + j_in;
        const float4* xp = (const float4*)(x + ((size_t)b * JJ + j) * II);
        float4 a = xp[0], c = xp[1];
        union { short8 v; __hip_bfloat16 h[8]; } u;
        u.h[0] = __float2bfloat16(a.x); u.h[1] = __float2bfloat16(a.y);
        u.h[2] = __float2bfloat16(a.z); u.h[3] = __float2bfloat16(a.w);
        u.h[4] = __float2bfloat16(c.x); u.h[5] = __float2bfloat16(c.y);
        u.h[6] = __float2bfloat16(c.z); u.h[7] = __float2bfloat16(c.w);
        *(short8*)(xbf + ((size_t)j * BB + b) * II) = u.v;
    } else {
        int idx = (blockIdx.x - KX_BLOCKS) * 256 + threadIdx.x;  // [0, K*J*16)
        int z    = idx & 15;
        int rest = idx >> 4;
        int j    = rest % JJ;
        int k    = rest / JJ;
        const float* src = W + (((size_t)k * JJ + j) * II) * ZZ + z;
        union { short8 v; __hip_bfloat16 h[8]; } u;
#pragma unroll
        for (int i = 0; i < II; ++i) u.h[i] = __float2bfloat16(src[i * ZZ]);
        *(short8*)(Wt + (((size_t)k * JJ + j) * ZZ + z) * II) = u.v;
    }
}

// ---- Pass A: usum_p[js][k][b][z] partials; 4 k x 6 j-quads x 32 b per wave ----
// grid (8 kt, 4 bt, NJSA), block 64. Each Wt load feeds 2 MFMAs (b-halves).
extern "C" __global__ __launch_bounds__(64)
void kA(const __hip_bfloat16* __restrict__ xbf,
        const __hip_bfloat16* __restrict__ Wt, float* __restrict__ usum_p) {
    const int kt = blockIdx.x;
    const int bt = blockIdx.y;
    const int js = blockIdx.z;
    const int l  = threadIdx.x;
    const int n  = l & 15;
    const int g  = l >> 4;
    const int b1 = bt * 32 + n;
    const int b2 = b1 + 16;

    short8 xv1[6], xv2[6];
#pragma unroll
    for (int q = 0; q < 6; ++q) {
        int j = (js * 6 + q) * 4 + g;
        xv1[q] = *(const short8*)(xbf + ((size_t)j * BB + b1) * II);
        xv2[q] = *(const short8*)(xbf + ((size_t)j * BB + b2) * II);
    }

    floatx4 acc1[4], acc2[4];
#pragma unroll
    for (int kk = 0; kk < 4; ++kk) {
        acc1[kk] = (floatx4){0.f, 0.f, 0.f, 0.f};
        acc2[kk] = (floatx4){0.f, 0.f, 0.f, 0.f};
    }

#pragma unroll
    for (int kk = 0; kk < 4; ++kk) {
        const int k = kt * 4 + kk;
#pragma unroll
        for (int q = 0; q < 6; ++q) {
            int j = (js * 6 + q) * 4 + g;
            short8 a = *(const short8*)(Wt + (((size_t)k * JJ + j) * ZZ + n) * II);
            acc1[kk] = __builtin_amdgcn_mfma_f32_16x16x32_bf16(a, xv1[q], acc1[kk], 0, 0, 0);
            acc2[kk] = __builtin_amdgcn_mfma_f32_16x16x32_bf16(a, xv2[q], acc2[kk], 0, 0, 0);
        }
    }
#pragma unroll
    for (int kk = 0; kk < 4; ++kk) {
        const int k = kt * 4 + kk;
        *(floatx4*)(usum_p + (((size_t)js * KK + k) * BB + b1) * ZZ + g * 4) = acc1[kk];
        *(floatx4*)(usum_p + (((size_t)js * KK + k) * BB + b2) * ZZ + g * 4) = acc2[kk];
    }
}

// ---- kR: usum = sum_js usum_p. 4-way js-split per output + shfl combine ----
extern "C" __global__ __launch_bounds__(256)
void kR(const float* __restrict__ usum_p, float* __restrict__ usum) {
    int p   = blockIdx.x * 256 + threadIdx.x;    // [0, 65536)
    int r   = p & 3;                             // js-split
    int idx = p >> 2;                            // float4 index [0,16384)
    floatx4 s = (floatx4){0.f, 0.f, 0.f, 0.f};
#pragma unroll 4
    for (int js = r * 12; js < r * 12 + 12; ++js)
        s += *(const floatx4*)(usum_p + (size_t)js * N_USUM + (size_t)idx * 4);
#pragma unroll
    for (int c = 0; c < 4; ++c) {
        s[c] += __shfl_xor(s[c], 1);
        s[c] += __shfl_xor(s[c], 2);
    }
    if (r == 0) *(floatx4*)(usum + (size_t)idx * 4) = s;
}

// ---- Fused B+C over (8-j, 32-b) tile, all 32 k in-block ----
extern "C" __global__ __launch_bounds__(256)
void kBC(const __hip_bfloat16* __restrict__ xbf,
         const __hip_bfloat16* __restrict__ Wt,
         const float* __restrict__ usum, const float* __restrict__ bias,
         float* __restrict__ sacc_p) {
    __shared__ float eS[KK * 8 * 32];   // 32 KB: e[k][jl][col], col = n or n+16
    __shared__ float Sw[4 * 8 * 32];    // 4 KB per-wave S partials
    __shared__ float rS[8 * 32];        // 1 KB: 1/S[jl][col]

    const int jt = blockIdx.x;          // 0..143
    const int bt = blockIdx.y;          // 0..3
    const int t  = threadIdx.x;
    const int w  = t >> 6;
    const int l  = t & 63;
    const int n  = l & 15;
    const int g  = l >> 4;
    const int b1 = bt * 32 + n;
    const int b2 = b1 + 16;
    const int j0 = jt * 8;

    short8 xv1[8], xv2[8];
#pragma unroll
    for (int jl = 0; jl < 8; ++jl) {
        xv1[jl] = *(const short8*)(xbf + ((size_t)(j0 + jl) * BB + b1) * II);
        xv2[jl] = *(const short8*)(xbf + ((size_t)(j0 + jl) * BB + b2) * II);
    }

    // ---- Phase 1: e + per-wave S ----
    float Sacc1[8], Sacc2[8];
#pragma unroll
    for (int jl = 0; jl < 8; ++jl) { Sacc1[jl] = 0.f; Sacc2[jl] = 0.f; }

#pragma unroll 2
    for (int kk = 0; kk < 8; ++kk) {
        const int k = w * 8 + kk;
        floatx4 us1 = *(const floatx4*)(usum + ((size_t)k * BB + b1) * ZZ + g * 4);
        floatx4 us2 = *(const floatx4*)(usum + ((size_t)k * BB + b2) * ZZ + g * 4);
#pragma unroll
        for (int jl = 0; jl < 8; ++jl) {
            short8 a = *(const short8*)(Wt + (((size_t)k * JJ + j0 + jl) * ZZ + n) * II);
            floatx4 c0 = {0.f, 0.f, 0.f, 0.f};
            floatx4 u1 = __builtin_amdgcn_mfma_f32_16x16x32_bf16(a, xv1[jl], c0, 0, 0, 0);
            floatx4 u2 = __builtin_amdgcn_mfma_f32_16x16x32_bf16(a, xv2[jl], c0, 0, 0, 0);
            float dp1 = u1[0] * us1[0];
            dp1 = fmaf(u1[1], us1[1], dp1);
            dp1 = fmaf(u1[2], us1[2], dp1);
            dp1 = fmaf(u1[3], us1[3], dp1);
            float dp2 = u2[0] * us2[0];
            dp2 = fmaf(u2[1], us2[1], dp2);
            dp2 = fmaf(u2[2], us2[2], dp2);
            dp2 = fmaf(u2[3], us2[3], dp2);
            dp1 += __shfl_xor(dp1, 16);
            dp1 += __shfl_xor(dp1, 32);
            dp2 += __shfl_xor(dp2, 16);
            dp2 += __shfl_xor(dp2, 32);
            float e1 = __expf(dp1 * 0.0625f);   // 0.25 softmax * 0.25 K-dup
            float e2 = __expf(dp2 * 0.0625f);
            Sacc1[jl] += e1;
            Sacc2[jl] += e2;
            if (g == 0) {
                eS[(k * 8 + jl) * 32 + n]      = e1;
                eS[(k * 8 + jl) * 32 + n + 16] = e2;
            }
        }
    }
    if (g == 0) {
#pragma unroll
        for (int jl = 0; jl < 8; ++jl) {
            Sw[(w * 8 + jl) * 32 + n]      = Sacc1[jl];
            Sw[(w * 8 + jl) * 32 + n + 16] = Sacc2[jl];
        }
    }
    __syncthreads();
    {
        int jl = t >> 5, col = t & 31;   // 256 threads exactly
        float s = Sw[(0 * 8 + jl) * 32 + col] + Sw[(1 * 8 + jl) * 32 + col]
                + Sw[(2 * 8 + jl) * 32 + col] + Sw[(3 * 8 + jl) * 32 + col];
        rS[jl * 32 + col] = __builtin_amdgcn_rcpf(s);
    }
    __syncthreads();

    // ---- Phase 2: sacc partial, c folded into B-operand ----
    float xf1[2][8], xf2[2][8];
#pragma unroll
    for (int quad = 0; quad < 2; ++quad) {
        union { short8 v; short s[8]; } xr1, xr2;
        int j = j0 + quad * 4 + g;
        xr1.v = *(const short8*)(xbf + ((size_t)j * BB + b1) * II);
        xr2.v = *(const short8*)(xbf + ((size_t)j * BB + b2) * II);
#pragma unroll
        for (int i = 0; i < II; ++i) {
            xf1[quad][i] = bf2f(xr1.s[i]);
            xf2[quad][i] = bf2f(xr2.s[i]);
        }
    }

    floatx4 acc1[8], acc2[8];
#pragma unroll
    for (int kk = 0; kk < 8; ++kk) {
        acc1[kk] = (floatx4){0.f, 0.f, 0.f, 0.f};
        acc2[kk] = (floatx4){0.f, 0.f, 0.f, 0.f};
    }

#pragma unroll 2
    for (int kk = 0; kk < 8; ++kk) {
        const int k = w * 8 + kk;
#pragma unroll
        for (int quad = 0; quad < 2; ++quad) {
            const int jl = quad * 4 + g;
            const int j  = j0 + jl;
            float bj = bias[(size_t)k * JJ + j];
            float c1 = fmaf(eS[(k * 8 + jl) * 32 + n],      rS[jl * 32 + n],      bj);
            float c2 = fmaf(eS[(k * 8 + jl) * 32 + n + 16], rS[jl * 32 + n + 16], bj);
            union { short8 v; short s[8]; } xs1, xs2;
#pragma unroll
            for (int i = 0; i < II; ++i) {
                __hip_bfloat16 h1 = __float2bfloat16(xf1[quad][i] * c1);
                __hip_bfloat16 h2 = __float2bfloat16(xf2[quad][i] * c2);
                __builtin_memcpy(&xs1.s[i], &h1, 2);
                __builtin_memcpy(&xs2.s[i], &h2, 2);
            }
            short8 a = *(const short8*)(Wt + (((size_t)k * JJ + j) * ZZ + n) * II);
            acc1[kk] = __builtin_amdgcn_mfma_f32_16x16x32_bf16(a, xs1.v, acc1[kk], 0, 0, 0);
            acc2[kk] = __builtin_amdgcn_mfma_f32_16x16x32_bf16(a, xs2.v, acc2[kk], 0, 0, 0);
        }
    }
#pragma unroll
    for (int kk = 0; kk < 8; ++kk) {
        const int k = w * 8 + kk;
        *(floatx4*)(sacc_p + (((size_t)jt * KK + k) * BB + b1) * ZZ + g * 4) = acc1[kk];
        *(floatx4*)(sacc_p + (((size_t)jt * KK + k) * BB + b2) * ZZ + g * 4) = acc2[kk];
    }
}

// ---- Pass D: 144-way reduce + squash. 4-way jt-split + shfl combine ----
// lane bits: [1:0]=r (jt-split), [3:2]=q (z-quarter), rest = (k,b)
extern "C" __global__ __launch_bounds__(256)
void kD(const float* __restrict__ sacc_p, float* __restrict__ out) {
    int p  = blockIdx.x * 256 + threadIdx.x;   // [0, KK*BB*16)
    int r  = p & 3;
    int q  = (p >> 2) & 3;
    int kb = p >> 4;
    int k  = kb >> 7;
    int b  = kb & 127;

    floatx4 v = (floatx4){0.f, 0.f, 0.f, 0.f};
#pragma unroll 6
    for (int jt = r * 36; jt < r * 36 + 36; ++jt)
        v += *(const floatx4*)(sacc_p + (((size_t)jt * KK + k) * BB + b) * ZZ + q * 4);

#pragma unroll
    for (int c = 0; c < 4; ++c) {
        v[c] += __shfl_xor(v[c], 1);
        v[c] += __shfl_xor(v[c], 2);
    }

    float nsq = v[0] * v[0];
    nsq = fmaf(v[1], v[1], nsq);
    nsq = fmaf(v[2], v[2], nsq);
    nsq = fmaf(v[3], v[3], nsq);
    nsq += __shfl_xor(nsq, 4);
    nsq += __shfl_xor(nsq, 8);

    float nr = sqrtf(nsq);
    float scale = (1.f - 1.f / (__expf(nr) + 1e-20f)) / (nr + 1e-20f);
    if (r == 0) {
        floatx4 o = v * scale;
        *(floatx4*)(out + ((size_t)b * KK + k) * ZZ + q * 4) = o;
    }
}

extern "C" void kernel_launch(void* const* d_in, const int* in_sizes, int n_in,
                              void* d_out, int out_size, void* d_ws, size_t ws_size,
                              hipStream_t stream) {
    const float* x    = (const float*)d_in[0];
    const float* W    = (const float*)d_in[1];
    const float* bias = (const float*)d_in[2];
    float*       out  = (float*)d_out;

    float* ws     = (float*)d_ws;
    float* usum   = ws;
    float* usum_p = usum + N_USUM;
    float* sacc_p = usum_p + N_USUMP;
    __hip_bfloat16* xbf = (__hip_bfloat16*)(sacc_p + N_SACCP);
    __hip_bfloat16* Wt  = xbf + (size_t)JJ * BB * II;

    // No memset: every workspace word is written before it is read.

    kP<<<KX_BLOCKS + KW_BLOCKS, 256, 0, stream>>>(x, W, xbf, Wt);
    kA<<<dim3(8, 4, NJSA), 64, 0, stream>>>(xbf, Wt, usum_p);
    kR<<<(KK * BB * ZZ) / 256, 256, 0, stream>>>(usum_p, usum);
    kBC<<<dim3(NJT, 4), 256, 0, stream>>>(xbf, Wt, usum, bias, sacc_p);
    kD<<<(KK * BB * 16) / 256, 256, 0, stream>>>(sacc_p, out);
}